// Round 2
// baseline (1748.900 us; speedup 1.0000x reference)
//
#include <hip/hip_runtime.h>
#include <stdint.h>

typedef unsigned long long u64;
typedef __attribute__((ext_vector_type(8))) short bf16x8;   // 8 bf16 = 4 VGPRs
typedef __attribute__((ext_vector_type(4))) float f32x4;

__device__ __forceinline__ unsigned short f2bf(float f) {
    unsigned x = __float_as_uint(f);
    unsigned r = (x + 0x7fffu + ((x >> 16) & 1u)) >> 16;   // RNE
    return (unsigned short)r;
}
__device__ __forceinline__ constexpr int cmax2(int a, int b) { return a > b ? a : b; }

// ---------------------------------------------------------------------------
// Kernel 1: farthest point sampling (f32 I/O). One block per batch, 512 thr.
// Bit-exact vs numpy: ((dx*dx+dy*dy)+dz*dz), fminf chain, argmax-first-tie
// via (distbits, 4095-j) lexicographic max. 32-bit ops only.
// ---------------------------------------------------------------------------
__global__ __launch_bounds__(512) void fps_kernel(const float* __restrict__ xyz,
                                                  float* __restrict__ newxyz) {
    const int b = blockIdx.x;
    const int t = threadIdx.x;
    __shared__ float xs[4096], ys[4096], zs[4096];
    __shared__ unsigned sd[2][8];
    __shared__ int si[2][8];

    union { float4 v[6]; float f[24]; } u;
    const float4* src = reinterpret_cast<const float4*>(xyz + (size_t)b * 12288) + t * 6;
#pragma unroll
    for (int w = 0; w < 6; ++w) u.v[w] = src[w];
    float px[8], py[8], pz[8], dist[8];
#pragma unroll
    for (int i = 0; i < 8; ++i) {
        px[i] = u.f[3 * i + 0];
        py[i] = u.f[3 * i + 1];
        pz[i] = u.f[3 * i + 2];
        const int j = t * 8 + i;
        xs[j] = px[i]; ys[j] = py[i]; zs[j] = pz[i];
        dist[i] = 1e10f;
    }
    __syncthreads();

    int far = 0;
    for (int k = 0; k < 1024; ++k) {
        if (t == 0) {
            const size_t o = ((size_t)b * 1024 + k) * 3;
            newxyz[o + 0] = xs[far];
            newxyz[o + 1] = ys[far];
            newxyz[o + 2] = zs[far];
        }
        const float cx = xs[far], cy = ys[far], cz = zs[far];
        float v = -1.0f; int jj = 0;
#pragma unroll
        for (int i = 0; i < 8; ++i) {
            const float dx = px[i] - cx, dy = py[i] - cy, dz = pz[i] - cz;
            const float d = __fadd_rn(__fadd_rn(__fmul_rn(dx, dx), __fmul_rn(dy, dy)),
                                      __fmul_rn(dz, dz));
            const float nd = fminf(dist[i], d);
            dist[i] = nd;
            if (nd > v) { v = nd; jj = i; }   // strict >: smallest local idx on tie
        }
        unsigned kd = __float_as_uint(v);             // v >= 0: bits are monotone
        unsigned ki = (unsigned)(4095 - (t * 8 + jj)); // max ki == min j
#pragma unroll
        for (int off = 32; off > 0; off >>= 1) {
            const unsigned od = __shfl_xor(kd, off, 64);
            const unsigned oi = __shfl_xor(ki, off, 64);
            const bool g = (od > kd) || (od == kd && oi > ki);
            kd = g ? od : kd;
            ki = g ? oi : ki;
        }
        const int p = k & 1;                 // double-buffer: safe w/ 1 barrier
        if ((t & 63) == 0) { sd[p][t >> 6] = kd; si[p][t >> 6] = (int)ki; }
        __syncthreads();
        unsigned bd = sd[p][0]; int bi = si[p][0];
#pragma unroll
        for (int w = 1; w < 8; ++w) {
            const unsigned od = sd[p][w]; const int oi = si[p][w];
            if (od > bd || (od == bd && oi > bi)) { bd = od; bi = oi; }
        }
        far = (4095 - bi) & 4095;
    }
}

// ---------------------------------------------------------------------------
// Kernel 2: ball query, all 3 radii in one pass (f32 in, u16 idx out).
// One wave per (b,s). Bit-exact predicate vs numpy (radius^2 folds to f32).
// ---------------------------------------------------------------------------
__global__ __launch_bounds__(256) void ballq_kernel(const float* __restrict__ xyz,
                                                    const float* __restrict__ newxyz,
                                                    unsigned short* __restrict__ idx0,
                                                    unsigned short* __restrict__ idx1,
                                                    unsigned short* __restrict__ idx2) {
    const int wave = threadIdx.x >> 6;
    const int lane = threadIdx.x & 63;
    const int g = blockIdx.x * 4 + wave;   // g = b*1024 + s
    const int b = g >> 10;

    const float* nc = newxyz + (size_t)g * 3;
    const float cx = nc[0], cy = nc[1], cz = nc[2];

    int cnt0 = 0, cnt1 = 0, cnt2 = 0;
    int f0 = 0, f1 = 0, f2 = 0;
    unsigned short* o0 = idx0 + (size_t)g * 16;
    unsigned short* o1 = idx1 + (size_t)g * 32;
    unsigned short* o2 = idx2 + (size_t)g * 128;
    const float* base = xyz + (size_t)b * 12288;

    for (int it = 0; it < 64; ++it) {
        const int j = it * 64 + lane;
        const float* p = base + j * 3;
        const float dx = p[0] - cx;
        const float dy = p[1] - cy;
        const float dz = p[2] - cz;
        const float d2 = __fadd_rn(__fadd_rn(__fmul_rn(dx, dx), __fmul_rn(dy, dy)),
                                   __fmul_rn(dz, dz));
        const bool p0 = d2 < 0.01f;   // f32(0.1*0.1)
        const bool p1 = d2 < 0.04f;   // f32(0.2*0.2)
        const bool p2 = d2 < 0.16f;   // f32(0.4*0.4)
        const u64 m0 = __ballot(p0);
        const u64 m1 = __ballot(p1);
        const u64 m2 = __ballot(p2);
        const u64 lower = (((u64)1) << lane) - 1;

        if (cnt0 < 16) {
            if (cnt0 == 0 && m0) f0 = it * 64 + __builtin_ctzll(m0);
            const int pos = cnt0 + (int)__builtin_popcountll(m0 & lower);
            if (p0 && pos < 16) o0[pos] = (unsigned short)j;
            cnt0 += (int)__builtin_popcountll(m0);
        }
        if (cnt1 < 32) {
            if (cnt1 == 0 && m1) f1 = it * 64 + __builtin_ctzll(m1);
            const int pos = cnt1 + (int)__builtin_popcountll(m1 & lower);
            if (p1 && pos < 32) o1[pos] = (unsigned short)j;
            cnt1 += (int)__builtin_popcountll(m1);
        }
        if (cnt2 < 128) {
            if (cnt2 == 0 && m2) f2 = it * 64 + __builtin_ctzll(m2);
            const int pos = cnt2 + (int)__builtin_popcountll(m2 & lower);
            if (p2 && pos < 128) o2[pos] = (unsigned short)j;
            cnt2 += (int)__builtin_popcountll(m2);
        }
        if (cnt0 >= 16 && cnt1 >= 32 && cnt2 >= 128) break;
    }
    for (int pos = cnt0 + lane; pos < 16; pos += 64) o0[pos] = (unsigned short)f0;
    for (int pos = cnt1 + lane; pos < 32; pos += 64) o1[pos] = (unsigned short)f1;
    for (int pos = cnt2 + lane; pos < 128; pos += 64) o2[pos] = (unsigned short)f2;
}

// ---------------------------------------------------------------------------
// MLP helpers
// ---------------------------------------------------------------------------
template <int Cin, int Kp, int Cout, int SW>
__device__ __forceinline__ void load_weights_part(const float* __restrict__ w,
                                                  const float* __restrict__ bias,
                                                  unsigned short* Wbuf, float* bbuf,
                                                  int tid, int noff, int ld) {
    for (int e = tid; e < Cout * Kp; e += 256) {
        const int n = e % Cout, k = e / Cout;
        Wbuf[n * SW + k] = (k < Cin) ? f2bf(w[k * ld + noff + n]) : (unsigned short)0;
    }
    for (int e = tid; e < Cout; e += 256) bbuf[e] = bias[noff + e];
}

// One wave computes MW rows x Cout cols of one layer.
// A (m89/m120): A[m=lane&15][k=quad*8+j]; B staged transposed [n][k] with
// n=lane&15, k=quad*8+j; C/D: col=lane&15, row=quad*4+reg.
template <int MW, int Kp, int Cout, int SIN, int SW, int SOUT, bool LAST>
__device__ __forceinline__ void layer_mfma(const unsigned short* __restrict__ src,
                                           unsigned short* __restrict__ dst,
                                           const unsigned short* __restrict__ Wbuf,
                                           const float* __restrict__ bbuf,
                                           float* __restrict__ Mx,
                                           int lane, int mslice) {
    constexpr int MT = MW / 16;
    constexpr int NT = Cout / 16;
    const int ml = lane & 15;
    const int quad = lane >> 4;

    f32x4 acc[MT][NT];
#pragma unroll
    for (int mt = 0; mt < MT; ++mt)
#pragma unroll
        for (int nt = 0; nt < NT; ++nt) acc[mt][nt] = (f32x4){0.f, 0.f, 0.f, 0.f};

#pragma unroll
    for (int ks = 0; ks < Kp; ks += 32) {
        bf16x8 afr[MT], bfr[NT];
#pragma unroll
        for (int mt = 0; mt < MT; ++mt)
            afr[mt] = *reinterpret_cast<const bf16x8*>(
                src + (mslice * MW + mt * 16 + ml) * SIN + ks + quad * 8);
#pragma unroll
        for (int nt = 0; nt < NT; ++nt)
            bfr[nt] = *reinterpret_cast<const bf16x8*>(
                Wbuf + (nt * 16 + ml) * SW + ks + quad * 8);
#pragma unroll
        for (int mt = 0; mt < MT; ++mt)
#pragma unroll
            for (int nt = 0; nt < NT; ++nt)
                acc[mt][nt] = __builtin_amdgcn_mfma_f32_16x16x32_bf16(
                    afr[mt], bfr[nt], acc[mt][nt], 0, 0, 0);
    }

#pragma unroll
    for (int nt = 0; nt < NT; ++nt) {
        const int col = nt * 16 + ml;
        const float bv = bbuf[col];
        if constexpr (!LAST) {
#pragma unroll
            for (int mt = 0; mt < MT; ++mt)
#pragma unroll
                for (int r = 0; r < 4; ++r) {
                    const float v = fmaxf(acc[mt][nt][r] + bv, 0.0f);
                    dst[(mslice * MW + mt * 16 + quad * 4 + r) * SOUT + col] = f2bf(v);
                }
        } else {
            float mx = 0.0f;   // relu floor folds into the max
#pragma unroll
            for (int mt = 0; mt < MT; ++mt)
#pragma unroll
                for (int r = 0; r < 4; ++r) mx = fmaxf(mx, acc[mt][nt][r] + bv);
            mx = fmaxf(mx, __shfl_xor(mx, 16, 64));
            mx = fmaxf(mx, __shfl_xor(mx, 32, 64));
            if (quad == 0)
                atomicMax(reinterpret_cast<int*>(Mx + col), __float_as_int(mx));
        }
    }
}

// ---------------------------------------------------------------------------
// Kernel 3: grouping + 3-layer MLP + max-pool, one branch per instantiation.
// NG groups per block, WPG waves per group (NG*WPG == 4). f32 in/out,
// bf16 internal (MFMA).
// ---------------------------------------------------------------------------
template <int NS, int C1, int C2, int C3, int NG, int WPG, int CH_OFF>
__global__ __launch_bounds__(256) void mlp_kernel(
    const float* __restrict__ xyz,
    const float* __restrict__ points,
    const float* __restrict__ newxyz,
    const unsigned short* __restrict__ idx,
    const float* __restrict__ w1, const float* __restrict__ b1,
    const float* __restrict__ w2, const float* __restrict__ b2,
    const float* __restrict__ w3, const float* __restrict__ b3,
    float* __restrict__ outfeat) {
    constexpr int SA = 104;            // stride for 96-wide A buffer (+8 pad)
    constexpr int SB = C1 + 8;
    constexpr int SW1 = 104, SW2 = C1 + 8, SW3 = C2 + 8;
    constexpr int NH = (C3 > 64) ? 2 : 1;   // split layer-3 N to cap LDS
    constexpr int C3P = C3 / NH;
    constexpr int WSZ = cmax2(cmax2(C1 * SW1, C2 * SW2), C3P * SW3);
    constexpr int MW = NS / WPG;

    __shared__ __align__(16) unsigned short Abuf[NG][NS][SA];
    __shared__ __align__(16) unsigned short Bbuf[NG][NS][SB];
    __shared__ __align__(16) unsigned short Wbuf[WSZ];
    __shared__ float bbuf[128];
    __shared__ float Mx[NG][C3];
    __shared__ unsigned short idxbuf[NG][NS];

    const int tid = threadIdx.x;
    const int lane = tid & 63;
    const int wave = tid >> 6;
    const int gl = wave / WPG;
    const int mslice = wave % WPG;

    for (int e = tid; e < NG * NS; e += 256)
        (&idxbuf[0][0])[e] = idx[(size_t)blockIdx.x * (NG * NS) + e];
    for (int e = tid; e < NG * C3; e += 256) (&Mx[0][0])[e] = 0.0f;
    load_weights_part<67, 96, C1, SW1>(w1, b1, Wbuf, bbuf, tid, 0, C1);
    __syncthreads();

    // gather: 4 threads per row (16 channels each); q==3 adds g_xyz + zero pad
    for (int rr = tid >> 2; rr < NG * NS; rr += 64) {
        const int q = tid & 3;
        const int g = rr / NS, kk = rr % NS;
        const int gg = blockIdx.x * NG + g;
        const int bb = gg >> 10;
        const int id = idxbuf[g][kk] & 4095;
        const float4* s4 = reinterpret_cast<const float4*>(
            points + (((size_t)bb * 4096 + id) << 6) + q * 16);
        const float4 c0 = s4[0], c1 = s4[1], c2 = s4[2], c3 = s4[3];
        union { uint4 o[2]; unsigned short h[16]; } t16;
        const float cc[16] = {c0.x, c0.y, c0.z, c0.w, c1.x, c1.y, c1.z, c1.w,
                              c2.x, c2.y, c2.z, c2.w, c3.x, c3.y, c3.z, c3.w};
#pragma unroll
        for (int i = 0; i < 16; ++i) t16.h[i] = f2bf(cc[i]);
        *reinterpret_cast<uint4*>(&Abuf[g][kk][q * 16]) = t16.o[0];
        *reinterpret_cast<uint4*>(&Abuf[g][kk][q * 16 + 8]) = t16.o[1];
        if (q == 3) {
            const float* pz = xyz + ((size_t)bb * 4096 + id) * 3;
            const float* nc = newxyz + (size_t)gg * 3;
            Abuf[g][kk][64] = f2bf(pz[0] - nc[0]);
            Abuf[g][kk][65] = f2bf(pz[1] - nc[1]);
            Abuf[g][kk][66] = f2bf(pz[2] - nc[2]);
#pragma unroll
            for (int c = 67; c < 72; ++c) Abuf[g][kk][c] = 0;
            *reinterpret_cast<uint4*>(&Abuf[g][kk][72]) = (uint4){0, 0, 0, 0};
            *reinterpret_cast<uint4*>(&Abuf[g][kk][80]) = (uint4){0, 0, 0, 0};
            *reinterpret_cast<uint4*>(&Abuf[g][kk][88]) = (uint4){0, 0, 0, 0};
        }
    }
    __syncthreads();

    // layer 1: 96(67) -> C1
    layer_mfma<MW, 96, C1, SA, SW1, SB, false>(&Abuf[gl][0][0], &Bbuf[gl][0][0],
                                               Wbuf, bbuf, nullptr, lane, mslice);
    __syncthreads();
    load_weights_part<C1, C1, C2, SW2>(w2, b2, Wbuf, bbuf, tid, 0, C2);
    __syncthreads();
    // layer 2: C1 -> C2
    layer_mfma<MW, C1, C2, SB, SW2, SA, false>(&Bbuf[gl][0][0], &Abuf[gl][0][0],
                                               Wbuf, bbuf, nullptr, lane, mslice);
    __syncthreads();
    // layer 3: C2 -> C3 (in NH halves), fused bias+relu+max
    for (int h = 0; h < NH; ++h) {
        load_weights_part<C2, C2, C3P, SW3>(w3, b3, Wbuf, bbuf, tid, h * C3P, C3);
        __syncthreads();
        layer_mfma<MW, C2, C3P, SA, SW3, 0, true>(&Abuf[gl][0][0], nullptr,
                                                  Wbuf, bbuf, &Mx[gl][0] + h * C3P,
                                                  lane, mslice);
        __syncthreads();
    }

    for (int e = tid; e < NG * C3; e += 256) {
        const int g = e / C3, c = e % C3;
        const size_t gg = (size_t)blockIdx.x * NG + g;
        outfeat[gg * 320 + CH_OFF + c] = (&Mx[0][0])[e];
    }
}

// ---------------------------------------------------------------------------
extern "C" void kernel_launch(void* const* d_in, const int* in_sizes, int n_in,
                              void* d_out, int out_size, void* d_ws, size_t ws_size,
                              hipStream_t stream) {
    (void)in_sizes; (void)n_in; (void)out_size; (void)ws_size;
    const float* xyz = (const float*)d_in[0];
    const float* points = (const float*)d_in[1];
    const float* W[3][3];
    const float* Bi[3][3];
    int p = 2;
    for (int bi = 0; bi < 3; ++bi)
        for (int li = 0; li < 3; ++li) {
            W[bi][li] = (const float*)d_in[p++];
            Bi[bi][li] = (const float*)d_in[p++];
        }
    float* newxyz = (float*)d_out;                  // 8*1024*3
    float* outfeat = (float*)d_out + 8 * 1024 * 3;  // 8*1024*320

    unsigned short* wsu = (unsigned short*)d_ws;    // 2.9 MB total (u16 indices)
    unsigned short* idx0 = wsu;                        // 8192*16
    unsigned short* idx1 = wsu + (size_t)8192 * 16;    // 8192*32
    unsigned short* idx2 = wsu + (size_t)8192 * 48;    // 8192*128

    fps_kernel<<<dim3(8), dim3(512), 0, stream>>>(xyz, newxyz);
    ballq_kernel<<<dim3(2048), dim3(256), 0, stream>>>(xyz, newxyz, idx0, idx1, idx2);
    mlp_kernel<16, 32, 32, 64, 4, 1, 0><<<dim3(2048), dim3(256), 0, stream>>>(
        xyz, points, newxyz, idx0,
        W[0][0], Bi[0][0], W[0][1], Bi[0][1], W[0][2], Bi[0][2], outfeat);
    mlp_kernel<32, 64, 64, 128, 4, 1, 64><<<dim3(2048), dim3(256), 0, stream>>>(
        xyz, points, newxyz, idx1,
        W[1][0], Bi[1][0], W[1][1], Bi[1][1], W[1][2], Bi[1][2], outfeat);
    mlp_kernel<128, 64, 96, 128, 1, 4, 192><<<dim3(8192), dim3(256), 0, stream>>>(
        xyz, points, newxyz, idx2,
        W[2][0], Bi[2][0], W[2][1], Bi[2][1], W[2][2], Bi[2][2], outfeat);
}

// Round 3
// 1262.343 us; speedup vs baseline: 1.3854x; 1.3854x over previous
//
#include <hip/hip_runtime.h>
#include <stdint.h>

typedef unsigned long long u64;
typedef __attribute__((ext_vector_type(8))) short bf16x8;   // 8 bf16 = 4 VGPRs
typedef __attribute__((ext_vector_type(4))) float f32x4;

__device__ __forceinline__ unsigned short f2bf(float f) {
    unsigned x = __float_as_uint(f);
    unsigned r = (x + 0x7fffu + ((x >> 16) & 1u)) >> 16;   // RNE
    return (unsigned short)r;
}
__device__ __forceinline__ constexpr int cmax2(int a, int b) { return a > b ? a : b; }

// ---------------------------------------------------------------------------
// Kernel 1: farthest point sampling (f32 I/O). One block per batch.
// 256 threads (4 waves = 1/SIMD), 16 pts/thread in registers.
// Bit-exact vs numpy: ((dx*dx+dy*dy)+dz*dz), fminf chain, argmax-first-tie.
// Reduction: float-max tree + smallest-idx scan -> u64 key (distbits, 4095-j)
// -> 6-level wave xor-reduce -> 4 LDS slots -> 1 barrier -> 2-level reduce.
// ---------------------------------------------------------------------------
__global__ __launch_bounds__(256) void fps_kernel(const float* __restrict__ xyz,
                                                  float* __restrict__ newxyz) {
    const int b = blockIdx.x;
    const int t = threadIdx.x;
    const int lane = t & 63;
    const int wave = t >> 6;
    __shared__ float xs[4096], ys[4096], zs[4096];
    __shared__ u64 slot[2][4];

    float px[16], py[16], pz[16], dist[16];
    {
        union { float4 v[12]; float f[48]; } u;
        const float4* src =
            reinterpret_cast<const float4*>(xyz + (size_t)b * 12288) + t * 12;
#pragma unroll
        for (int w = 0; w < 12; ++w) u.v[w] = src[w];
#pragma unroll
        for (int i = 0; i < 16; ++i) {
            px[i] = u.f[3 * i + 0];
            py[i] = u.f[3 * i + 1];
            pz[i] = u.f[3 * i + 2];
            const int j = t * 16 + i;
            xs[j] = px[i]; ys[j] = py[i]; zs[j] = pz[i];
            dist[i] = 1e10f;
        }
    }
    __syncthreads();

    int far = 0;
    for (int k = 0; k < 1024; ++k) {
        const float cx = xs[far], cy = ys[far], cz = zs[far];
        if (t == 0) {
            const size_t o = ((size_t)b * 1024 + k) * 3;
            newxyz[o + 0] = cx; newxyz[o + 1] = cy; newxyz[o + 2] = cz;
        }
#pragma unroll
        for (int i = 0; i < 16; ++i) {
            const float dx = px[i] - cx, dy = py[i] - cy, dz = pz[i] - cz;
            const float d = __fadd_rn(__fadd_rn(__fmul_rn(dx, dx), __fmul_rn(dy, dy)),
                                      __fmul_rn(dz, dz));
            dist[i] = fminf(dist[i], d);
        }
        // max tree (no idx), then smallest-index equality scan (tie-exact).
        float m8[8], m4[4], m2[2], bv;
#pragma unroll
        for (int i = 0; i < 8; ++i) m8[i] = fmaxf(dist[i], dist[i + 8]);
#pragma unroll
        for (int i = 0; i < 4; ++i) m4[i] = fmaxf(m8[i], m8[i + 4]);
        m2[0] = fmaxf(m4[0], m4[2]); m2[1] = fmaxf(m4[1], m4[3]);
        bv = fmaxf(m2[0], m2[1]);
        int bj = 15;
#pragma unroll
        for (int i = 14; i >= 0; --i) bj = (dist[i] == bv) ? i : bj;

        u64 key = ((u64)__float_as_uint(bv) << 32) |
                  (unsigned)(4095 - (t * 16 + bj));
#pragma unroll
        for (int off = 1; off < 64; off <<= 1) {
            const u64 o = __shfl_xor(key, off, 64);
            key = (o > key) ? o : key;
        }
        if (lane == 0) slot[k & 1][wave] = key;
        __syncthreads();
        u64 kk = slot[k & 1][lane & 3];
        {
            u64 o = __shfl_xor(kk, 1, 64); kk = (o > kk) ? o : kk;
            o = __shfl_xor(kk, 2, 64);     kk = (o > kk) ? o : kk;
        }
        far = 4095 - (int)(unsigned)(kk & 0xffffffffull);
    }
}

// ---------------------------------------------------------------------------
// Kernel 2: ball query, all 3 radii in one pass (f32 in, u16 idx out).
// One wave per (b,s). Bit-exact predicate vs numpy (radius^2 folds to f32).
// ---------------------------------------------------------------------------
__global__ __launch_bounds__(256) void ballq_kernel(const float* __restrict__ xyz,
                                                    const float* __restrict__ newxyz,
                                                    unsigned short* __restrict__ idx0,
                                                    unsigned short* __restrict__ idx1,
                                                    unsigned short* __restrict__ idx2) {
    const int wave = threadIdx.x >> 6;
    const int lane = threadIdx.x & 63;
    const int g = blockIdx.x * 4 + wave;   // g = b*1024 + s
    const int b = g >> 10;

    const float* nc = newxyz + (size_t)g * 3;
    const float cx = nc[0], cy = nc[1], cz = nc[2];

    int cnt0 = 0, cnt1 = 0, cnt2 = 0;
    int f0 = 0, f1 = 0, f2 = 0;
    unsigned short* o0 = idx0 + (size_t)g * 16;
    unsigned short* o1 = idx1 + (size_t)g * 32;
    unsigned short* o2 = idx2 + (size_t)g * 128;
    const float* base = xyz + (size_t)b * 12288;

    for (int it = 0; it < 64; ++it) {
        const int j = it * 64 + lane;
        const float* p = base + j * 3;
        const float dx = p[0] - cx;
        const float dy = p[1] - cy;
        const float dz = p[2] - cz;
        const float d2 = __fadd_rn(__fadd_rn(__fmul_rn(dx, dx), __fmul_rn(dy, dy)),
                                   __fmul_rn(dz, dz));
        const bool p0 = d2 < 0.01f;   // f32(0.1*0.1)
        const bool p1 = d2 < 0.04f;   // f32(0.2*0.2)
        const bool p2 = d2 < 0.16f;   // f32(0.4*0.4)
        const u64 m0 = __ballot(p0);
        const u64 m1 = __ballot(p1);
        const u64 m2 = __ballot(p2);
        const u64 lower = (((u64)1) << lane) - 1;

        if (cnt0 < 16) {
            if (cnt0 == 0 && m0) f0 = it * 64 + __builtin_ctzll(m0);
            const int pos = cnt0 + (int)__builtin_popcountll(m0 & lower);
            if (p0 && pos < 16) o0[pos] = (unsigned short)j;
            cnt0 += (int)__builtin_popcountll(m0);
        }
        if (cnt1 < 32) {
            if (cnt1 == 0 && m1) f1 = it * 64 + __builtin_ctzll(m1);
            const int pos = cnt1 + (int)__builtin_popcountll(m1 & lower);
            if (p1 && pos < 32) o1[pos] = (unsigned short)j;
            cnt1 += (int)__builtin_popcountll(m1);
        }
        if (cnt2 < 128) {
            if (cnt2 == 0 && m2) f2 = it * 64 + __builtin_ctzll(m2);
            const int pos = cnt2 + (int)__builtin_popcountll(m2 & lower);
            if (p2 && pos < 128) o2[pos] = (unsigned short)j;
            cnt2 += (int)__builtin_popcountll(m2);
        }
        if (cnt0 >= 16 && cnt1 >= 32 && cnt2 >= 128) break;
    }
    for (int pos = cnt0 + lane; pos < 16; pos += 64) o0[pos] = (unsigned short)f0;
    for (int pos = cnt1 + lane; pos < 32; pos += 64) o1[pos] = (unsigned short)f1;
    for (int pos = cnt2 + lane; pos < 128; pos += 64) o2[pos] = (unsigned short)f2;
}

// ---------------------------------------------------------------------------
// MLP helpers
// ---------------------------------------------------------------------------
template <int Cin, int Kp, int Cout, int SW>
__device__ __forceinline__ void load_weights_part(const float* __restrict__ w,
                                                  const float* __restrict__ bias,
                                                  unsigned short* Wbuf, float* bbuf,
                                                  int tid, int noff, int ld) {
    for (int e = tid; e < Cout * Kp; e += 256) {
        const int n = e % Cout, k = e / Cout;
        Wbuf[n * SW + k] = (k < Cin) ? f2bf(w[k * ld + noff + n]) : (unsigned short)0;
    }
    for (int e = tid; e < Cout; e += 256) bbuf[e] = bias[noff + e];
}

// One wave computes MW rows x Cout cols of one layer.
// A (m89/m120): A[m=lane&15][k=quad*8+j]; B staged transposed [n][k] with
// n=lane&15, k=quad*8+j; C/D: col=lane&15, row=quad*4+reg.
template <int MW, int Kp, int Cout, int SIN, int SW, int SOUT, bool LAST>
__device__ __forceinline__ void layer_mfma(const unsigned short* __restrict__ src,
                                           unsigned short* __restrict__ dst,
                                           const unsigned short* __restrict__ Wbuf,
                                           const float* __restrict__ bbuf,
                                           float* __restrict__ Mx,
                                           int lane, int mslice) {
    constexpr int MT = MW / 16;
    constexpr int NT = Cout / 16;
    const int ml = lane & 15;
    const int quad = lane >> 4;

    f32x4 acc[MT][NT];
#pragma unroll
    for (int mt = 0; mt < MT; ++mt)
#pragma unroll
        for (int nt = 0; nt < NT; ++nt) acc[mt][nt] = (f32x4){0.f, 0.f, 0.f, 0.f};

#pragma unroll
    for (int ks = 0; ks < Kp; ks += 32) {
        bf16x8 afr[MT], bfr[NT];
#pragma unroll
        for (int mt = 0; mt < MT; ++mt)
            afr[mt] = *reinterpret_cast<const bf16x8*>(
                src + (mslice * MW + mt * 16 + ml) * SIN + ks + quad * 8);
#pragma unroll
        for (int nt = 0; nt < NT; ++nt)
            bfr[nt] = *reinterpret_cast<const bf16x8*>(
                Wbuf + (nt * 16 + ml) * SW + ks + quad * 8);
#pragma unroll
        for (int mt = 0; mt < MT; ++mt)
#pragma unroll
            for (int nt = 0; nt < NT; ++nt)
                acc[mt][nt] = __builtin_amdgcn_mfma_f32_16x16x32_bf16(
                    afr[mt], bfr[nt], acc[mt][nt], 0, 0, 0);
    }

#pragma unroll
    for (int nt = 0; nt < NT; ++nt) {
        const int col = nt * 16 + ml;
        const float bv = bbuf[col];
        if constexpr (!LAST) {
#pragma unroll
            for (int mt = 0; mt < MT; ++mt)
#pragma unroll
                for (int r = 0; r < 4; ++r) {
                    const float v = fmaxf(acc[mt][nt][r] + bv, 0.0f);
                    dst[(mslice * MW + mt * 16 + quad * 4 + r) * SOUT + col] = f2bf(v);
                }
        } else {
            float mx = 0.0f;   // relu floor folds into the max
#pragma unroll
            for (int mt = 0; mt < MT; ++mt)
#pragma unroll
                for (int r = 0; r < 4; ++r) mx = fmaxf(mx, acc[mt][nt][r] + bv);
            mx = fmaxf(mx, __shfl_xor(mx, 16, 64));
            mx = fmaxf(mx, __shfl_xor(mx, 32, 64));
            if (quad == 0)
                atomicMax(reinterpret_cast<int*>(Mx + col), __float_as_int(mx));
        }
    }
}

// ---------------------------------------------------------------------------
// Kernel 3: grouping + 3-layer MLP + max-pool, one branch per instantiation.
// NG groups per block, WPG waves per group (NG*WPG == 4). f32 in/out,
// bf16 internal (MFMA).
// ---------------------------------------------------------------------------
template <int NS, int C1, int C2, int C3, int NG, int WPG, int CH_OFF>
__global__ __launch_bounds__(256) void mlp_kernel(
    const float* __restrict__ xyz,
    const float* __restrict__ points,
    const float* __restrict__ newxyz,
    const unsigned short* __restrict__ idx,
    const float* __restrict__ w1, const float* __restrict__ b1,
    const float* __restrict__ w2, const float* __restrict__ b2,
    const float* __restrict__ w3, const float* __restrict__ b3,
    float* __restrict__ outfeat) {
    constexpr int SA = 104;            // stride for 96-wide A buffer (+8 pad)
    constexpr int SB = C1 + 8;
    constexpr int SW1 = 104, SW2 = C1 + 8, SW3 = C2 + 8;
    constexpr int NH = (C3 > 64) ? 2 : 1;   // split layer-3 N to cap LDS
    constexpr int C3P = C3 / NH;
    constexpr int WSZ = cmax2(cmax2(C1 * SW1, C2 * SW2), C3P * SW3);
    constexpr int MW = NS / WPG;

    __shared__ __align__(16) unsigned short Abuf[NG][NS][SA];
    __shared__ __align__(16) unsigned short Bbuf[NG][NS][SB];
    __shared__ __align__(16) unsigned short Wbuf[WSZ];
    __shared__ float bbuf[128];
    __shared__ float Mx[NG][C3];
    __shared__ unsigned short idxbuf[NG][NS];

    const int tid = threadIdx.x;
    const int lane = tid & 63;
    const int wave = tid >> 6;
    const int gl = wave / WPG;
    const int mslice = wave % WPG;

    for (int e = tid; e < NG * NS; e += 256)
        (&idxbuf[0][0])[e] = idx[(size_t)blockIdx.x * (NG * NS) + e];
    for (int e = tid; e < NG * C3; e += 256) (&Mx[0][0])[e] = 0.0f;
    load_weights_part<67, 96, C1, SW1>(w1, b1, Wbuf, bbuf, tid, 0, C1);
    __syncthreads();

    // gather: 4 threads per row (16 channels each); q==3 adds g_xyz + zero pad
    for (int rr = tid >> 2; rr < NG * NS; rr += 64) {
        const int q = tid & 3;
        const int g = rr / NS, kk = rr % NS;
        const int gg = blockIdx.x * NG + g;
        const int bb = gg >> 10;
        const int id = idxbuf[g][kk] & 4095;
        const float4* s4 = reinterpret_cast<const float4*>(
            points + (((size_t)bb * 4096 + id) << 6) + q * 16);
        const float4 c0 = s4[0], c1 = s4[1], c2 = s4[2], c3 = s4[3];
        union { uint4 o[2]; unsigned short h[16]; } t16;
        const float cc[16] = {c0.x, c0.y, c0.z, c0.w, c1.x, c1.y, c1.z, c1.w,
                              c2.x, c2.y, c2.z, c2.w, c3.x, c3.y, c3.z, c3.w};
#pragma unroll
        for (int i = 0; i < 16; ++i) t16.h[i] = f2bf(cc[i]);
        *reinterpret_cast<uint4*>(&Abuf[g][kk][q * 16]) = t16.o[0];
        *reinterpret_cast<uint4*>(&Abuf[g][kk][q * 16 + 8]) = t16.o[1];
        if (q == 3) {
            const float* pz = xyz + ((size_t)bb * 4096 + id) * 3;
            const float* nc = newxyz + (size_t)gg * 3;
            Abuf[g][kk][64] = f2bf(pz[0] - nc[0]);
            Abuf[g][kk][65] = f2bf(pz[1] - nc[1]);
            Abuf[g][kk][66] = f2bf(pz[2] - nc[2]);
#pragma unroll
            for (int c = 67; c < 72; ++c) Abuf[g][kk][c] = 0;
            *reinterpret_cast<uint4*>(&Abuf[g][kk][72]) = (uint4){0, 0, 0, 0};
            *reinterpret_cast<uint4*>(&Abuf[g][kk][80]) = (uint4){0, 0, 0, 0};
            *reinterpret_cast<uint4*>(&Abuf[g][kk][88]) = (uint4){0, 0, 0, 0};
        }
    }
    __syncthreads();

    // layer 1: 96(67) -> C1
    layer_mfma<MW, 96, C1, SA, SW1, SB, false>(&Abuf[gl][0][0], &Bbuf[gl][0][0],
                                               Wbuf, bbuf, nullptr, lane, mslice);
    __syncthreads();
    load_weights_part<C1, C1, C2, SW2>(w2, b2, Wbuf, bbuf, tid, 0, C2);
    __syncthreads();
    // layer 2: C1 -> C2
    layer_mfma<MW, C1, C2, SB, SW2, SA, false>(&Bbuf[gl][0][0], &Abuf[gl][0][0],
                                               Wbuf, bbuf, nullptr, lane, mslice);
    __syncthreads();
    // layer 3: C2 -> C3 (in NH halves), fused bias+relu+max
    for (int h = 0; h < NH; ++h) {
        load_weights_part<C2, C2, C3P, SW3>(w3, b3, Wbuf, bbuf, tid, h * C3P, C3);
        __syncthreads();
        layer_mfma<MW, C2, C3P, SA, SW3, 0, true>(&Abuf[gl][0][0], nullptr,
                                                  Wbuf, bbuf, &Mx[gl][0] + h * C3P,
                                                  lane, mslice);
        __syncthreads();
    }

    for (int e = tid; e < NG * C3; e += 256) {
        const int g = e / C3, c = e % C3;
        const size_t gg = (size_t)blockIdx.x * NG + g;
        outfeat[gg * 320 + CH_OFF + c] = (&Mx[0][0])[e];
    }
}

// ---------------------------------------------------------------------------
extern "C" void kernel_launch(void* const* d_in, const int* in_sizes, int n_in,
                              void* d_out, int out_size, void* d_ws, size_t ws_size,
                              hipStream_t stream) {
    (void)in_sizes; (void)n_in; (void)out_size; (void)ws_size;
    const float* xyz = (const float*)d_in[0];
    const float* points = (const float*)d_in[1];
    const float* W[3][3];
    const float* Bi[3][3];
    int p = 2;
    for (int bi = 0; bi < 3; ++bi)
        for (int li = 0; li < 3; ++li) {
            W[bi][li] = (const float*)d_in[p++];
            Bi[bi][li] = (const float*)d_in[p++];
        }
    float* newxyz = (float*)d_out;                  // 8*1024*3
    float* outfeat = (float*)d_out + 8 * 1024 * 3;  // 8*1024*320

    unsigned short* wsu = (unsigned short*)d_ws;    // 2.9 MB total (u16 indices)
    unsigned short* idx0 = wsu;                        // 8192*16
    unsigned short* idx1 = wsu + (size_t)8192 * 16;    // 8192*32
    unsigned short* idx2 = wsu + (size_t)8192 * 48;    // 8192*128

    fps_kernel<<<dim3(8), dim3(256), 0, stream>>>(xyz, newxyz);
    ballq_kernel<<<dim3(2048), dim3(256), 0, stream>>>(xyz, newxyz, idx0, idx1, idx2);
    mlp_kernel<16, 32, 32, 64, 4, 1, 0><<<dim3(2048), dim3(256), 0, stream>>>(
        xyz, points, newxyz, idx0,
        W[0][0], Bi[0][0], W[0][1], Bi[0][1], W[0][2], Bi[0][2], outfeat);
    mlp_kernel<32, 64, 64, 128, 4, 1, 64><<<dim3(2048), dim3(256), 0, stream>>>(
        xyz, points, newxyz, idx1,
        W[1][0], Bi[1][0], W[1][1], Bi[1][1], W[1][2], Bi[1][2], outfeat);
    mlp_kernel<128, 64, 96, 128, 1, 4, 192><<<dim3(8192), dim3(256), 0, stream>>>(
        xyz, points, newxyz, idx2,
        W[2][0], Bi[2][0], W[2][1], Bi[2][1], W[2][2], Bi[2][2], outfeat);
}

// Round 4
// 1015.232 us; speedup vs baseline: 1.7227x; 1.2434x over previous
//
#include <hip/hip_runtime.h>
#include <stdint.h>

typedef unsigned long long u64;
typedef __attribute__((ext_vector_type(8))) short bf16x8;   // 8 bf16 = 4 VGPRs
typedef __attribute__((ext_vector_type(4))) float f32x4;

__device__ __forceinline__ unsigned short f2bf(float f) {
    unsigned x = __float_as_uint(f);
    unsigned r = (x + 0x7fffu + ((x >> 16) & 1u)) >> 16;   // RNE
    return (unsigned short)r;
}
__device__ __forceinline__ constexpr int cmax2(int a, int b) { return a > b ? a : b; }

// Wave64 max-reduce of a non-negative f32 at VALU speed (DPP, no LDS hops).
// After the 6 steps lane 63 holds the max of all 64 lanes.
__device__ __forceinline__ float wave_max_dpp(float v) {
#define DPP_MAX_STEP(ctrl)                                                     \
    v = fmaxf(v, __int_as_float(__builtin_amdgcn_update_dpp(                   \
               0, __float_as_int(v), (ctrl), 0xf, 0xf, true)))
    DPP_MAX_STEP(0xB1);   // quad_perm [1,0,3,2]  : xor 1
    DPP_MAX_STEP(0x4E);   // quad_perm [2,3,0,1]  : xor 2
    DPP_MAX_STEP(0x141);  // row_half_mirror      : xor 4 (quads uniform)
    DPP_MAX_STEP(0x140);  // row_mirror           : xor 8 (8-groups uniform)
    DPP_MAX_STEP(0x142);  // row_bcast15          : rows 0->1, 2->3
    DPP_MAX_STEP(0x143);  // row_bcast31          : rows 01->23
#undef DPP_MAX_STEP
    return __int_as_float(__builtin_amdgcn_readlane(__float_as_int(v), 63));
}

// ---------------------------------------------------------------------------
// Kernel 1: farthest point sampling (f32 I/O). One block per batch.
// 256 threads (4 waves), 16 pts/thread in registers.
// Bit-exact vs numpy: ((dx*dx+dy*dy)+dz*dz), fminf chain, argmax-first-tie.
// Per-iter reduction: reg max-tree + smallest-idx scan -> DPP wave max ->
// ballot/ctz/readlane winner -> 1 u64 slot per wave -> barrier -> 4-way max.
// ---------------------------------------------------------------------------
__global__ __launch_bounds__(256) void fps_kernel(const float* __restrict__ xyz,
                                                  float* __restrict__ newxyz) {
    const int b = blockIdx.x;
    const int t = threadIdx.x;
    const int lane = t & 63;
    const int wave = t >> 6;
    __shared__ float xs[4096], ys[4096], zs[4096];
    __shared__ __align__(32) u64 slot[2][4];

    float px[16], py[16], pz[16], dist[16];
    {
        union { float4 v[12]; float f[48]; } u;
        const float4* src =
            reinterpret_cast<const float4*>(xyz + (size_t)b * 12288) + t * 12;
#pragma unroll
        for (int w = 0; w < 12; ++w) u.v[w] = src[w];
#pragma unroll
        for (int i = 0; i < 16; ++i) {
            px[i] = u.f[3 * i + 0];
            py[i] = u.f[3 * i + 1];
            pz[i] = u.f[3 * i + 2];
            const int j = t * 16 + i;
            xs[j] = px[i]; ys[j] = py[i]; zs[j] = pz[i];
            dist[i] = 1e10f;
        }
    }
    __syncthreads();

    int far = 0;
    for (int k = 0; k < 1024; ++k) {
        const float cx = xs[far], cy = ys[far], cz = zs[far];
        if (t == 0) {
            const size_t o = ((size_t)b * 1024 + k) * 3;
            newxyz[o + 0] = cx; newxyz[o + 1] = cy; newxyz[o + 2] = cz;
        }
#pragma unroll
        for (int i = 0; i < 16; ++i) {
            const float dx = px[i] - cx, dy = py[i] - cy, dz = pz[i] - cz;
            const float d = __fadd_rn(__fadd_rn(__fmul_rn(dx, dx), __fmul_rn(dy, dy)),
                                      __fmul_rn(dz, dz));
            dist[i] = fminf(dist[i], d);
        }
        // thread-local max tree, then smallest-index equality scan (tie-exact)
        float m8[8], m4[4], m2[2], bv;
#pragma unroll
        for (int i = 0; i < 8; ++i) m8[i] = fmaxf(dist[i], dist[i + 8]);
#pragma unroll
        for (int i = 0; i < 4; ++i) m4[i] = fmaxf(m8[i], m8[i + 4]);
        m2[0] = fmaxf(m4[0], m4[2]); m2[1] = fmaxf(m4[1], m4[3]);
        bv = fmaxf(m2[0], m2[1]);
        int bj = 15;
#pragma unroll
        for (int i = 14; i >= 0; --i) bj = (dist[i] == bv) ? i : bj;
        const int myidx = t * 16 + bj;

        // wave max at VALU speed; winner = first lane matching (smallest idx)
        const float wmax = wave_max_dpp(bv);
        const u64 mask = __ballot(bv == wmax);
        const int fl = (int)__builtin_ctzll(mask);
        const int widx = __builtin_amdgcn_readlane(myidx, fl);

        if (lane == 0)
            slot[k & 1][wave] =
                ((u64)__float_as_uint(wmax) << 32) | (unsigned)(4095 - widx);
        __syncthreads();
        const ulonglong2 a =
            *reinterpret_cast<const ulonglong2*>(&slot[k & 1][0]);
        const ulonglong2 c =
            *reinterpret_cast<const ulonglong2*>(&slot[k & 1][2]);
        const u64 m01 = (a.x > a.y) ? a.x : a.y;
        const u64 m23 = (c.x > c.y) ? c.x : c.y;
        const u64 mm = (m01 > m23) ? m01 : m23;
        far = 4095 - (int)(unsigned)(mm & 0xffffffffull);
    }
}

// ---------------------------------------------------------------------------
// Kernel 2: ball query, all 3 radii in one pass (f32 in, u16 idx out).
// One wave per (b,s). Bit-exact predicate vs numpy (radius^2 folds to f32).
// ---------------------------------------------------------------------------
__global__ __launch_bounds__(256) void ballq_kernel(const float* __restrict__ xyz,
                                                    const float* __restrict__ newxyz,
                                                    unsigned short* __restrict__ idx0,
                                                    unsigned short* __restrict__ idx1,
                                                    unsigned short* __restrict__ idx2) {
    const int wave = threadIdx.x >> 6;
    const int lane = threadIdx.x & 63;
    const int g = blockIdx.x * 4 + wave;   // g = b*1024 + s
    const int b = g >> 10;

    const float* nc = newxyz + (size_t)g * 3;
    const float cx = nc[0], cy = nc[1], cz = nc[2];

    int cnt0 = 0, cnt1 = 0, cnt2 = 0;
    int f0 = 0, f1 = 0, f2 = 0;
    unsigned short* o0 = idx0 + (size_t)g * 16;
    unsigned short* o1 = idx1 + (size_t)g * 32;
    unsigned short* o2 = idx2 + (size_t)g * 128;
    const float* base = xyz + (size_t)b * 12288;

    for (int it = 0; it < 64; ++it) {
        const int j = it * 64 + lane;
        const float* p = base + j * 3;
        const float dx = p[0] - cx;
        const float dy = p[1] - cy;
        const float dz = p[2] - cz;
        const float d2 = __fadd_rn(__fadd_rn(__fmul_rn(dx, dx), __fmul_rn(dy, dy)),
                                   __fmul_rn(dz, dz));
        const bool p0 = d2 < 0.01f;   // f32(0.1*0.1)
        const bool p1 = d2 < 0.04f;   // f32(0.2*0.2)
        const bool p2 = d2 < 0.16f;   // f32(0.4*0.4)
        const u64 m0 = __ballot(p0);
        const u64 m1 = __ballot(p1);
        const u64 m2 = __ballot(p2);
        const u64 lower = (((u64)1) << lane) - 1;

        if (cnt0 < 16) {
            if (cnt0 == 0 && m0) f0 = it * 64 + __builtin_ctzll(m0);
            const int pos = cnt0 + (int)__builtin_popcountll(m0 & lower);
            if (p0 && pos < 16) o0[pos] = (unsigned short)j;
            cnt0 += (int)__builtin_popcountll(m0);
        }
        if (cnt1 < 32) {
            if (cnt1 == 0 && m1) f1 = it * 64 + __builtin_ctzll(m1);
            const int pos = cnt1 + (int)__builtin_popcountll(m1 & lower);
            if (p1 && pos < 32) o1[pos] = (unsigned short)j;
            cnt1 += (int)__builtin_popcountll(m1);
        }
        if (cnt2 < 128) {
            if (cnt2 == 0 && m2) f2 = it * 64 + __builtin_ctzll(m2);
            const int pos = cnt2 + (int)__builtin_popcountll(m2 & lower);
            if (p2 && pos < 128) o2[pos] = (unsigned short)j;
            cnt2 += (int)__builtin_popcountll(m2);
        }
        if (cnt0 >= 16 && cnt1 >= 32 && cnt2 >= 128) break;
    }
    for (int pos = cnt0 + lane; pos < 16; pos += 64) o0[pos] = (unsigned short)f0;
    for (int pos = cnt1 + lane; pos < 32; pos += 64) o1[pos] = (unsigned short)f1;
    for (int pos = cnt2 + lane; pos < 128; pos += 64) o2[pos] = (unsigned short)f2;
}

// ---------------------------------------------------------------------------
// MLP helpers
// ---------------------------------------------------------------------------
template <int Cin, int Kp, int Cout, int SW>
__device__ __forceinline__ void load_weights_part(const float* __restrict__ w,
                                                  const float* __restrict__ bias,
                                                  unsigned short* Wbuf, float* bbuf,
                                                  int tid, int noff, int ld) {
    for (int e = tid; e < Cout * Kp; e += 256) {
        const int n = e % Cout, k = e / Cout;
        Wbuf[n * SW + k] = (k < Cin) ? f2bf(w[k * ld + noff + n]) : (unsigned short)0;
    }
    for (int e = tid; e < Cout; e += 256) bbuf[e] = bias[noff + e];
}

// One wave computes MW rows x Cout cols of one layer.
// A (m89/m120): A[m=lane&15][k=quad*8+j]; B staged transposed [n][k] with
// n=lane&15, k=quad*8+j; C/D: col=lane&15, row=quad*4+reg.
template <int MW, int Kp, int Cout, int SIN, int SW, int SOUT, bool LAST>
__device__ __forceinline__ void layer_mfma(const unsigned short* __restrict__ src,
                                           unsigned short* __restrict__ dst,
                                           const unsigned short* __restrict__ Wbuf,
                                           const float* __restrict__ bbuf,
                                           float* __restrict__ Mx,
                                           int lane, int mslice) {
    constexpr int MT = MW / 16;
    constexpr int NT = Cout / 16;
    const int ml = lane & 15;
    const int quad = lane >> 4;

    f32x4 acc[MT][NT];
#pragma unroll
    for (int mt = 0; mt < MT; ++mt)
#pragma unroll
        for (int nt = 0; nt < NT; ++nt) acc[mt][nt] = (f32x4){0.f, 0.f, 0.f, 0.f};

#pragma unroll
    for (int ks = 0; ks < Kp; ks += 32) {
        bf16x8 afr[MT], bfr[NT];
#pragma unroll
        for (int mt = 0; mt < MT; ++mt)
            afr[mt] = *reinterpret_cast<const bf16x8*>(
                src + (mslice * MW + mt * 16 + ml) * SIN + ks + quad * 8);
#pragma unroll
        for (int nt = 0; nt < NT; ++nt)
            bfr[nt] = *reinterpret_cast<const bf16x8*>(
                Wbuf + (nt * 16 + ml) * SW + ks + quad * 8);
#pragma unroll
        for (int mt = 0; mt < MT; ++mt)
#pragma unroll
            for (int nt = 0; nt < NT; ++nt)
                acc[mt][nt] = __builtin_amdgcn_mfma_f32_16x16x32_bf16(
                    afr[mt], bfr[nt], acc[mt][nt], 0, 0, 0);
    }

#pragma unroll
    for (int nt = 0; nt < NT; ++nt) {
        const int col = nt * 16 + ml;
        const float bv = bbuf[col];
        if constexpr (!LAST) {
#pragma unroll
            for (int mt = 0; mt < MT; ++mt)
#pragma unroll
                for (int r = 0; r < 4; ++r) {
                    const float v = fmaxf(acc[mt][nt][r] + bv, 0.0f);
                    dst[(mslice * MW + mt * 16 + quad * 4 + r) * SOUT + col] = f2bf(v);
                }
        } else {
            float mx = 0.0f;   // relu floor folds into the max
#pragma unroll
            for (int mt = 0; mt < MT; ++mt)
#pragma unroll
                for (int r = 0; r < 4; ++r) mx = fmaxf(mx, acc[mt][nt][r] + bv);
            mx = fmaxf(mx, __shfl_xor(mx, 16, 64));
            mx = fmaxf(mx, __shfl_xor(mx, 32, 64));
            if (quad == 0)
                atomicMax(reinterpret_cast<int*>(Mx + col), __float_as_int(mx));
        }
    }
}

// ---------------------------------------------------------------------------
// Kernel 3: grouping + 3-layer MLP + max-pool, one branch per instantiation.
// NG groups per block, WPG waves per group (NG*WPG == 4). f32 in/out,
// bf16 internal (MFMA).
// ---------------------------------------------------------------------------
template <int NS, int C1, int C2, int C3, int NG, int WPG, int CH_OFF>
__global__ __launch_bounds__(256) void mlp_kernel(
    const float* __restrict__ xyz,
    const float* __restrict__ points,
    const float* __restrict__ newxyz,
    const unsigned short* __restrict__ idx,
    const float* __restrict__ w1, const float* __restrict__ b1,
    const float* __restrict__ w2, const float* __restrict__ b2,
    const float* __restrict__ w3, const float* __restrict__ b3,
    float* __restrict__ outfeat) {
    constexpr int SA = 104;            // stride for 96-wide A buffer (+8 pad)
    constexpr int SB = C1 + 8;
    constexpr int SW1 = 104, SW2 = C1 + 8, SW3 = C2 + 8;
    constexpr int NH = (C3 > 64) ? 2 : 1;   // split layer-3 N to cap LDS
    constexpr int C3P = C3 / NH;
    constexpr int WSZ = cmax2(cmax2(C1 * SW1, C2 * SW2), C3P * SW3);
    constexpr int MW = NS / WPG;

    __shared__ __align__(16) unsigned short Abuf[NG][NS][SA];
    __shared__ __align__(16) unsigned short Bbuf[NG][NS][SB];
    __shared__ __align__(16) unsigned short Wbuf[WSZ];
    __shared__ float bbuf[128];
    __shared__ float Mx[NG][C3];
    __shared__ unsigned short idxbuf[NG][NS];

    const int tid = threadIdx.x;
    const int lane = tid & 63;
    const int wave = tid >> 6;
    const int gl = wave / WPG;
    const int mslice = wave % WPG;

    for (int e = tid; e < NG * NS; e += 256)
        (&idxbuf[0][0])[e] = idx[(size_t)blockIdx.x * (NG * NS) + e];
    for (int e = tid; e < NG * C3; e += 256) (&Mx[0][0])[e] = 0.0f;
    load_weights_part<67, 96, C1, SW1>(w1, b1, Wbuf, bbuf, tid, 0, C1);
    __syncthreads();

    // gather: 4 threads per row (16 channels each); q==3 adds g_xyz + zero pad
    for (int rr = tid >> 2; rr < NG * NS; rr += 64) {
        const int q = tid & 3;
        const int g = rr / NS, kk = rr % NS;
        const int gg = blockIdx.x * NG + g;
        const int bb = gg >> 10;
        const int id = idxbuf[g][kk] & 4095;
        const float4* s4 = reinterpret_cast<const float4*>(
            points + (((size_t)bb * 4096 + id) << 6) + q * 16);
        const float4 c0 = s4[0], c1 = s4[1], c2 = s4[2], c3 = s4[3];
        union { uint4 o[2]; unsigned short h[16]; } t16;
        const float cc[16] = {c0.x, c0.y, c0.z, c0.w, c1.x, c1.y, c1.z, c1.w,
                              c2.x, c2.y, c2.z, c2.w, c3.x, c3.y, c3.z, c3.w};
#pragma unroll
        for (int i = 0; i < 16; ++i) t16.h[i] = f2bf(cc[i]);
        *reinterpret_cast<uint4*>(&Abuf[g][kk][q * 16]) = t16.o[0];
        *reinterpret_cast<uint4*>(&Abuf[g][kk][q * 16 + 8]) = t16.o[1];
        if (q == 3) {
            const float* pz = xyz + ((size_t)bb * 4096 + id) * 3;
            const float* nc = newxyz + (size_t)gg * 3;
            Abuf[g][kk][64] = f2bf(pz[0] - nc[0]);
            Abuf[g][kk][65] = f2bf(pz[1] - nc[1]);
            Abuf[g][kk][66] = f2bf(pz[2] - nc[2]);
#pragma unroll
            for (int c = 67; c < 72; ++c) Abuf[g][kk][c] = 0;
            *reinterpret_cast<uint4*>(&Abuf[g][kk][72]) = (uint4){0, 0, 0, 0};
            *reinterpret_cast<uint4*>(&Abuf[g][kk][80]) = (uint4){0, 0, 0, 0};
            *reinterpret_cast<uint4*>(&Abuf[g][kk][88]) = (uint4){0, 0, 0, 0};
        }
    }
    __syncthreads();

    // layer 1: 96(67) -> C1
    layer_mfma<MW, 96, C1, SA, SW1, SB, false>(&Abuf[gl][0][0], &Bbuf[gl][0][0],
                                               Wbuf, bbuf, nullptr, lane, mslice);
    __syncthreads();
    load_weights_part<C1, C1, C2, SW2>(w2, b2, Wbuf, bbuf, tid, 0, C2);
    __syncthreads();
    // layer 2: C1 -> C2
    layer_mfma<MW, C1, C2, SB, SW2, SA, false>(&Bbuf[gl][0][0], &Abuf[gl][0][0],
                                               Wbuf, bbuf, nullptr, lane, mslice);
    __syncthreads();
    // layer 3: C2 -> C3 (in NH halves), fused bias+relu+max
    for (int h = 0; h < NH; ++h) {
        load_weights_part<C2, C2, C3P, SW3>(w3, b3, Wbuf, bbuf, tid, h * C3P, C3);
        __syncthreads();
        layer_mfma<MW, C2, C3P, SA, SW3, 0, true>(&Abuf[gl][0][0], nullptr,
                                                  Wbuf, bbuf, &Mx[gl][0] + h * C3P,
                                                  lane, mslice);
        __syncthreads();
    }

    for (int e = tid; e < NG * C3; e += 256) {
        const int g = e / C3, c = e % C3;
        const size_t gg = (size_t)blockIdx.x * NG + g;
        outfeat[gg * 320 + CH_OFF + c] = (&Mx[0][0])[e];
    }
}

// ---------------------------------------------------------------------------
extern "C" void kernel_launch(void* const* d_in, const int* in_sizes, int n_in,
                              void* d_out, int out_size, void* d_ws, size_t ws_size,
                              hipStream_t stream) {
    (void)in_sizes; (void)n_in; (void)out_size; (void)ws_size;
    const float* xyz = (const float*)d_in[0];
    const float* points = (const float*)d_in[1];
    const float* W[3][3];
    const float* Bi[3][3];
    int p = 2;
    for (int bi = 0; bi < 3; ++bi)
        for (int li = 0; li < 3; ++li) {
            W[bi][li] = (const float*)d_in[p++];
            Bi[bi][li] = (const float*)d_in[p++];
        }
    float* newxyz = (float*)d_out;                  // 8*1024*3
    float* outfeat = (float*)d_out + 8 * 1024 * 3;  // 8*1024*320

    unsigned short* wsu = (unsigned short*)d_ws;    // 2.9 MB total (u16 indices)
    unsigned short* idx0 = wsu;                        // 8192*16
    unsigned short* idx1 = wsu + (size_t)8192 * 16;    // 8192*32
    unsigned short* idx2 = wsu + (size_t)8192 * 48;    // 8192*128

    fps_kernel<<<dim3(8), dim3(256), 0, stream>>>(xyz, newxyz);
    ballq_kernel<<<dim3(2048), dim3(256), 0, stream>>>(xyz, newxyz, idx0, idx1, idx2);
    mlp_kernel<16, 32, 32, 64, 4, 1, 0><<<dim3(2048), dim3(256), 0, stream>>>(
        xyz, points, newxyz, idx0,
        W[0][0], Bi[0][0], W[0][1], Bi[0][1], W[0][2], Bi[0][2], outfeat);
    mlp_kernel<32, 64, 64, 128, 4, 1, 64><<<dim3(2048), dim3(256), 0, stream>>>(
        xyz, points, newxyz, idx1,
        W[1][0], Bi[1][0], W[1][1], Bi[1][1], W[1][2], Bi[1][2], outfeat);
    mlp_kernel<128, 64, 96, 128, 1, 4, 192><<<dim3(8192), dim3(256), 0, stream>>>(
        xyz, points, newxyz, idx2,
        W[2][0], Bi[2][0], W[2][1], Bi[2][1], W[2][2], Bi[2][2], outfeat);
}